// Round 4
// baseline (265.279 us; speedup 1.0000x reference)
//
#include <hip/hip_runtime.h>
#include <stdint.h>

// DetectionBaseline: SSD post-process. R4:
//  - register/wave bitonic sort (8 barriers instead of 66 barrier-passes)
//  - prep kernel factoring batch-shared softmax(m,sum) + box decode (20x dedup)
//  - chunk=128 greedy NMS (9 serial phases), ballot-built row masks
// Output (flat f32): boxes [16,200,4] | labels [16,200] (as float) | scores [16,200].

#define A_N     1280
#define CF      20
#define NC      21
#define B_N     16
#define TOPK    200
#define THREADS 256
#define SORT_N  2048
#define CH      128

// ws layout (bytes): [0,512000) per-class kept keys; then prep data
#define KEYS_BYTES     (B_N * CF * TOPK * 8)              // 512000
#define BOX_OFF_BYTES  KEYS_BYTES                          // float4 boxes [16*1280]
#define MS_OFF_BYTES   (BOX_OFF_BYTES + B_N * A_N * 16)    // float2 (m,sum) [16*1280]
#define WS_NEED_BYTES  (MS_OFF_BYTES + B_N * A_N * 8)      // 1003520 total

static __device__ __forceinline__ uint64_t pack_key(float sc, uint32_t idx) {
    // softmax scores positive -> float bits monotone. ~bits => ascending key = descending
    // score; low 32 bits = index => ties break toward smaller index (stable argsort / top_k).
    return ((uint64_t)(uint32_t)(~__float_as_uint(sc)) << 32) | (uint64_t)idx;
}

static __device__ __forceinline__ float box_area(const float4 v) {
    return (v.z - v.x) * (v.w - v.y);
}

static __device__ __forceinline__ bool iou_gt(const float4 a, const float aarea,
                                              const float4 b, const float barea) {
    // ref-exact: inter/(area_a+area_b-inter) > 0.45
    const float lx = fmaxf(a.x, b.x);
    const float ly = fmaxf(a.y, b.y);
    const float rx = fminf(a.z, b.z);
    const float ry = fminf(a.w, b.w);
    const float wx = fmaxf(rx - lx, 0.0f);
    const float wy = fmaxf(ry - ly, 0.0f);
    const float inter = wx * wy;
    const float uni   = aarea + barea - inter;
    return inter / uni > 0.45f;
}

static __device__ __forceinline__ float4 decode_box(const float4 lc, const float4 an) {
    const float cx = lc.x * an.z / 10.0f + an.x;
    const float cy = lc.y * an.w / 10.0f + an.y;
    const float w  = expf(lc.z / 5.0f) * an.z;
    const float h  = expf(lc.w / 5.0f) * an.w;
    float4 v;
    v.x = cx - w / 2.0f; v.y = cy - h / 2.0f;
    v.z = cx + w / 2.0f; v.w = cy + h / 2.0f;
    return v;
}

// ---- prep: per (b,a) decoded box + softmax (max, sum) -- shared across 20 classes ----
__global__ __launch_bounds__(THREADS)
void prep_kernel(const float* __restrict__ locs,
                 const float* __restrict__ scores,
                 const float* __restrict__ anchors,
                 float4* __restrict__ boxes_ws,
                 float2* __restrict__ ms_ws)
{
    const int g = blockIdx.x * THREADS + threadIdx.x;
    if (g >= B_N * A_N) return;
    const int a = g % A_N;
    boxes_ws[g] = decode_box(((const float4*)locs)[g], ((const float4*)anchors)[a]);
    const float* sp = scores + (size_t)g * NC;
    float m = sp[0];
    #pragma unroll
    for (int k = 1; k < NC; ++k) m = fmaxf(m, sp[k]);
    float sum = 0.0f;
    #pragma unroll
    for (int k = 0; k < NC; ++k) sum += expf(sp[k] - m);
    ms_ws[g] = make_float2(m, sum);
}

template <bool PREP>
__global__ __launch_bounds__(THREADS)
void nms_kernel(const float* __restrict__ locs,
                const float* __restrict__ scores,
                const float* __restrict__ anchors,
                const float4* __restrict__ boxes_ws,
                const float2* __restrict__ ms_ws,
                uint64_t* __restrict__ ws_keys)
{
    __shared__ uint64_t      skeys[SORT_N];   // 16 KB
    __shared__ float4        sbox[A_N];       // 20 KB
    __shared__ float4        schunk[CH];      // 2 KB
    __shared__ uint64_t      srow[CH][2];     // 2 KB row masks (128 bits per row)
    __shared__ float4        swbox[TOPK];     // winners
    __shared__ uint64_t      swkey[TOPK];
    __shared__ unsigned char sdead[CH];
    __shared__ int           sW;

    const int blk = blockIdx.x;
    const int b   = blk / CF;
    const int c   = blk % CF + 1;             // class channel 1..20
    const int t   = threadIdx.x;
    const int l   = t & 63;
    const int w   = t >> 6;

    // ---- prologue: boxes + class score keys ----
    #pragma unroll
    for (int i = 0; i < A_N / THREADS; ++i) {
        const int a = t + i * THREADS;
        float4 v; float m, sum;
        if (PREP) {
            v = boxes_ws[b * A_N + a];
            const float2 ms = ms_ws[b * A_N + a];
            m = ms.x; sum = ms.y;
        } else {
            v = decode_box(((const float4*)locs)[(size_t)b * A_N + a],
                           ((const float4*)anchors)[a]);
            const float* sp = scores + ((size_t)b * A_N + a) * NC;
            m = sp[0];
            #pragma unroll
            for (int k = 1; k < NC; ++k) m = fmaxf(m, sp[k]);
            sum = 0.0f;
            #pragma unroll
            for (int k = 0; k < NC; ++k) sum += expf(sp[k] - m);
        }
        sbox[a] = v;
        const float sl = scores[((size_t)b * A_N + a) * NC + c];
        const float sc = expf(sl - m) / sum;               // ref-exact softmax value
        skeys[a] = (sc > 0.01f) ? pack_key(sc, (uint32_t)a) : ~0ull;
    }
    for (int i = A_N + t; i < SORT_N; i += THREADS) skeys[i] = ~0ull;
    if (t == 0) sW = 0;
    __syncthreads();

    // ---- register/wave bitonic sort, element e = w*512 + r*64 + l ----
    uint64_t k[8];
    #pragma unroll
    for (int r = 0; r < 8; ++r) k[r] = skeys[(w << 9) + (r << 6) + l];

    for (int kk = 2; kk <= SORT_N; kk <<= 1) {
        for (int j = kk >> 1; j; j >>= 1) {
            if (j >= 512) {
                // cross-wave: LDS round trip
                __syncthreads();
                #pragma unroll
                for (int r = 0; r < 8; ++r) skeys[(w << 9) + (r << 6) + l] = k[r];
                __syncthreads();
                #pragma unroll
                for (int r = 0; r < 8; ++r) {
                    const int e = (w << 9) + (r << 6) + l;
                    const uint64_t o = skeys[e ^ j];
                    const bool keep_min = (((e & j) == 0) == ((e & kk) == 0));
                    const uint64_t mn = k[r] < o ? k[r] : o;
                    const uint64_t mx = k[r] < o ? o : k[r];
                    k[r] = keep_min ? mn : mx;
                }
            } else if (j >= 64) {
                // in-thread register exchange
                const int rb = j >> 6;
                #pragma unroll
                for (int r = 0; r < 8; ++r) {
                    if ((r & rb) == 0) {
                        const int p = r | rb;
                        const int e = (w << 9) + (r << 6) + l;
                        const bool up = ((e & kk) == 0);
                        const uint64_t x = k[r], y = k[p];
                        const uint64_t mn = x < y ? x : y;
                        const uint64_t mx = x < y ? y : x;
                        k[r] = up ? mn : mx;
                        k[p] = up ? mx : mn;
                    }
                }
            } else {
                // in-wave shuffle exchange
                #pragma unroll
                for (int r = 0; r < 8; ++r) {
                    const uint64_t o = (uint64_t)__shfl_xor((unsigned long long)k[r], j, 64);
                    const int e = (w << 9) + (r << 6) + l;
                    const bool keep_min = (((e & j) == 0) == ((e & kk) == 0));
                    const uint64_t mn = k[r] < o ? k[r] : o;
                    const uint64_t mx = k[r] < o ? o : k[r];
                    k[r] = keep_min ? mn : mx;
                }
            }
        }
    }
    __syncthreads();   // last LDS-pass readers done before overwrite
    #pragma unroll
    for (int r = 0; r < 8; ++r) skeys[(w << 9) + (r << 6) + l] = k[r];
    __syncthreads();

    // ---- chunked greedy NMS: 128 ranks per phase ----
    int W = 0;
    for (int cb = 0; cb < SORT_N; cb += CH) {
        if (skeys[cb] == ~0ull) break;        // sorted: rest of ranks invalid

        // phase A: gather chunk boxes + validity
        if (t < CH) {
            const uint64_t kc = skeys[cb + t];
            const bool v = (kc != ~0ull);
            schunk[t] = v ? sbox[(uint32_t)kc] : make_float4(-8.f, -8.f, -8.f, -8.f);
            sdead[t]  = v ? 0 : 1;
        }
        __syncthreads();

        // phase B: row masks via ballot (wave w: rows [32w,32w+32)) + cross-test vs winners
        const float4 cb0 = schunk[l];
        const float4 cb1 = schunk[64 + l];
        const float  ca0 = box_area(cb0);
        const float  ca1 = box_area(cb1);
        for (int r = w * 32; r < w * 32 + 32; ++r) {
            const float4 rbx = schunk[r];
            const float  ra  = box_area(rbx);
            const uint64_t m0 = __ballot(iou_gt(rbx, ra, cb0, ca0));
            const uint64_t m1 = __ballot(iou_gt(rbx, ra, cb1, ca1));
            if (l == 0) { srow[r][0] = m0; srow[r][1] = m1; }
        }
        {
            const int jj = t >> 1, h = t & 1;
            const float4 bj = schunk[jj];
            const float  aj = box_area(bj);
            int sup = 0;
            for (int w2 = h; w2 < W; w2 += 2) {
                const float4 bw = swbox[w2];
                if (iou_gt(bw, box_area(bw), bj, aj)) { sup = 1; break; }
            }
            sup |= __shfl_xor(sup, 1, 64);
            if (h == 0 && sup) sdead[jj] = 1;
        }
        __syncthreads();

        // phase C: wave 0 resolves the chunk in rank order
        if (t < 64) {
            bool al0 = !sdead[t];
            bool al1 = !sdead[64 + t];
            int Wl = W;
            while (true) {
                const unsigned long long bal0 = __ballot(al0);
                const unsigned long long bal1 = __ballot(al1);
                if (!(bal0 | bal1)) break;
                const int f = bal0 ? (__ffsll(bal0) - 1) : (64 + __ffsll(bal1) - 1);
                if (t == 0) { swkey[Wl] = skeys[cb + f]; swbox[Wl] = schunk[f]; }
                const uint64_t r0 = srow[f][0];          // uniform LDS reads
                const uint64_t r1 = srow[f][1];
                al0 = al0 && !((r0 >> t) & 1);           // winner self-clears (IoU=1)
                al1 = al1 && !((r1 >> t) & 1);
                ++Wl;
                if (Wl >= TOPK) break;                   // later winners can't reach output
            }
            if (t == 0) sW = Wl;
        }
        __syncthreads();
        W = sW;
        if (W >= TOPK) break;
    }

    // ---- write per-class kept list (already rank-sorted) ----
    const uint32_t  base = (uint32_t)(c - 1) * A_N;
    uint64_t* const out  = ws_keys + ((size_t)b * CF + (c - 1)) * TOPK;
    for (int kx = t; kx < TOPK; kx += THREADS) {
        if (kx < W) {
            const uint64_t kk2 = swkey[kx];
            out[kx] = (kk2 & 0xFFFFFFFF00000000ull) | (uint64_t)(base + (uint32_t)kk2);
        } else {
            out[kx] = ~0ull;
        }
    }
}

// Per batch: top-200 of 20 sorted 200-lists via truncated pairwise bitonic merges (R2/R3-verified).
__global__ __launch_bounds__(THREADS)
void merge_kernel(const float* __restrict__ locs,
                  const float* __restrict__ anchors,
                  const uint64_t* __restrict__ ws_keys,
                  float* __restrict__ out)
{
    __shared__ uint64_t Abuf[20][256];   // 40 KB
    __shared__ uint64_t Bbuf[10][256];   // 20 KB

    const int b = blockIdx.x;
    const int t = threadIdx.x;
    const uint64_t* const in = ws_keys + (size_t)b * CF * TOPK;

    for (int e = t; e < CF * 256; e += THREADS) {
        const int c = e >> 8, i = e & 255;
        Abuf[c][i] = (i < TOPK) ? in[c * TOPK + i] : ~0ull;
    }

    uint64_t (*src)[256] = Abuf;
    uint64_t (*dst)[256] = Bbuf;
    int n = CF;
    while (n > 1) {
        const int  nm    = n >> 1;
        const bool carry = (n & 1) != 0;
        __syncthreads();
        for (int e = t; e < nm * 256; e += THREADS) {
            const int mm = e >> 8, i = e & 255;
            const uint64_t x = src[2 * mm][i];
            const uint64_t y = src[2 * mm + 1][255 - i];
            dst[mm][i] = x < y ? x : y;              // lower-half extraction (bitonic)
        }
        if (carry)
            for (int i = t; i < 256; i += THREADS) dst[nm][i] = src[n - 1][i];
        for (int j = 128; j; j >>= 1) {
            __syncthreads();
            for (int pp = t; pp < nm * 128; pp += THREADS) {
                const int mm = pp >> 7, qq = pp & 127;
                const int i  = ((qq & ~(j - 1)) << 1) | (qq & (j - 1));
                const uint64_t x = dst[mm][i], y = dst[mm][i + j];
                if (y < x) { dst[mm][i] = y; dst[mm][i + j] = x; }
            }
        }
        uint64_t (*tmp)[256] = src; src = dst; dst = tmp;
        n = nm + (carry ? 1 : 0);
    }
    __syncthreads();

    if (t < TOPK) {
        const uint64_t k = src[0][t];
        float* const boxes_out  = out;                           // [B][TOPK][4]
        float* const labels_out = out + (size_t)B_N * TOPK * 4;  // [B][TOPK]
        float* const scores_out = out + (size_t)B_N * TOPK * 5;  // [B][TOPK]
        const size_t s = (size_t)b * TOPK + t;
        if (k == ~0ull) {
            boxes_out[s * 4 + 0] = 0.0f;
            boxes_out[s * 4 + 1] = 0.0f;
            boxes_out[s * 4 + 2] = 0.0f;
            boxes_out[s * 4 + 3] = 0.0f;
            labels_out[s] = 0.0f;
            scores_out[s] = 0.0f;
        } else {
            const uint32_t flat = (uint32_t)k;
            const int cls = flat / A_N;          // 0..19
            const int a   = flat - cls * A_N;
            const float sc = __uint_as_float(~(uint32_t)(k >> 32));
            const float4 v = decode_box(((const float4*)locs)[(size_t)b * A_N + a],
                                        ((const float4*)anchors)[a]);
            boxes_out[s * 4 + 0] = v.x;
            boxes_out[s * 4 + 1] = v.y;
            boxes_out[s * 4 + 2] = v.z;
            boxes_out[s * 4 + 3] = v.w;
            labels_out[s] = (float)(cls + 1);
            scores_out[s] = sc;
        }
    }
}

extern "C" void kernel_launch(void* const* d_in, const int* in_sizes, int n_in,
                              void* d_out, int out_size, void* d_ws, size_t ws_size,
                              hipStream_t stream) {
    const float* locs    = (const float*)d_in[0];
    const float* scores  = (const float*)d_in[1];
    const float* anchors = (const float*)d_in[2];
    // d_in[3] = top_k (always 200 per setup_inputs)
    uint64_t* ws_keys = (uint64_t*)d_ws;
    float*    outp    = (float*)d_out;

    const bool prep = (ws_size >= (size_t)WS_NEED_BYTES);
    float4* boxes_ws = (float4*)((char*)d_ws + BOX_OFF_BYTES);
    float2* ms_ws    = (float2*)((char*)d_ws + MS_OFF_BYTES);

    if (prep) {
        hipLaunchKernelGGL(prep_kernel, dim3((B_N * A_N + THREADS - 1) / THREADS),
                           dim3(THREADS), 0, stream, locs, scores, anchors, boxes_ws, ms_ws);
        hipLaunchKernelGGL((nms_kernel<true>), dim3(B_N * CF), dim3(THREADS), 0, stream,
                           locs, scores, anchors, boxes_ws, ms_ws, ws_keys);
    } else {
        hipLaunchKernelGGL((nms_kernel<false>), dim3(B_N * CF), dim3(THREADS), 0, stream,
                           locs, scores, anchors, boxes_ws, ms_ws, ws_keys);
    }
    hipLaunchKernelGGL(merge_kernel, dim3(B_N), dim3(THREADS), 0, stream,
                       locs, anchors, ws_keys, outp);
}